// Round 1
// baseline (632.295 us; speedup 1.0000x reference)
//
#include <hip/hip_runtime.h>
#include <cstdint>

#define NNODES 100000
#define NEDGES 1200000
#define INF 64
#define OUTF 32

// ---------------- degree accumulation ----------------
__global__ __launch_bounds__(256) void k_deg(const int* __restrict__ dst,
                                             float* __restrict__ deg) {
    int i = blockIdx.x * 256 + threadIdx.x;
    if (i < NEDGES) atomicAdd(&deg[dst[i]], 1.0f);
}

// norm = rsqrt(max(deg,1)) in place
__global__ __launch_bounds__(256) void k_norm(float* __restrict__ deg) {
    int i = blockIdx.x * 256 + threadIdx.x;
    if (i < NNODES) {
        float d = deg[i];
        deg[i] = rsqrtf(d < 1.0f ? 1.0f : d);
    }
}

// ---------------- h0 = X @ W^T  (project BEFORE propagation: 64->32) ----------
__global__ __launch_bounds__(256) void k_project(const float* __restrict__ feat,
                                                 const float* __restrict__ W,
                                                 float* __restrict__ h0) {
    __shared__ float Ws[OUTF][INF + 1];  // +1 pad: kills 32-way bank conflict
    __shared__ float Fs[8][INF];
    int tid = threadIdx.x;
    for (int i = tid; i < OUTF * INF; i += 256) Ws[i / INF][i % INF] = W[i];
    int node0 = blockIdx.x * 8;
    for (int i = tid; i < 8 * INF; i += 256) {
        int n = node0 + i / INF;
        Fs[i / INF][i % INF] = (n < NNODES) ? feat[(size_t)n * INF + (i % INF)] : 0.0f;
    }
    __syncthreads();
    int ln = tid >> 5, of = tid & 31;
    int n = node0 + ln;
    if (n < NNODES) {
        float acc = 0.0f;
#pragma unroll
        for (int k = 0; k < INF; ++k) acc += Fs[ln][k] * Ws[of][k];
        h0[(size_t)n * OUTF + of] = acc;
    }
}

// ---------------- one hop: hout[d,f] += norm[s]*norm[d]*hin[s,f] --------------
// 32 lanes per edge (one per feature). Norm product folds both the pre-scale
// (norm[s]) and post-scale (norm[d], distributes over the segment sum).
__global__ __launch_bounds__(256) void k_scatter(const float* __restrict__ hin,
                                                 float* __restrict__ hout,
                                                 const int* __restrict__ src,
                                                 const int* __restrict__ dst,
                                                 const float* __restrict__ norm) {
    int idx = blockIdx.x * 256 + threadIdx.x;
    int e = idx >> 5;
    if (e >= NEDGES) return;
    int f = idx & 31;
    int s = src[e], d = dst[e];
    float w = norm[s] * norm[d];
    atomicAdd(&hout[(size_t)d * OUTF + f], w * hin[(size_t)s * OUTF + f]);
}

// init d_out rows to bias b; last hop scatters on top (isolated nodes -> b)
__global__ __launch_bounds__(256) void k_biasinit(float* __restrict__ out,
                                                  const float* __restrict__ b) {
    int i = blockIdx.x * 256 + threadIdx.x;
    if (i < NNODES * OUTF) out[i] = b[i & (OUTF - 1)];
}

extern "C" void kernel_launch(void* const* d_in, const int* in_sizes, int n_in,
                              void* d_out, int out_size, void* d_ws, size_t ws_size,
                              hipStream_t stream) {
    const float* feat = (const float*)d_in[0];
    const int*   src  = (const int*)d_in[1];
    const int*   dst  = (const int*)d_in[2];
    const float* W    = (const float*)d_in[3];
    const float* b    = (const float*)d_in[4];
    float* out = (float*)d_out;

    char* ws = (char*)d_ws;
    float* norm = (float*)ws;                                   // 400 KB
    size_t off = ((size_t)NNODES * 4 + 255) & ~(size_t)255;
    float* h0 = (float*)(ws + off);                             // 12.8 MB
    float* h1 = (float*)(ws + off + (size_t)NNODES * OUTF * 4); // 12.8 MB

    const size_t hbytes = (size_t)NNODES * OUTF * 4;

    // degree + norm
    hipMemsetAsync(norm, 0, (size_t)NNODES * 4, stream);
    k_deg<<<(NEDGES + 255) / 256, 256, 0, stream>>>(dst, norm);
    k_norm<<<(NNODES + 255) / 256, 256, 0, stream>>>(norm);

    // project features 64 -> 32
    k_project<<<(NNODES + 7) / 8, 256, 0, stream>>>(feat, W, h0);

    const int sgrid = (NEDGES * 32 + 255) / 256;

    // hop 1: h0 -> h1
    hipMemsetAsync(h1, 0, hbytes, stream);
    k_scatter<<<sgrid, 256, 0, stream>>>(h0, h1, src, dst, norm);
    // hop 2: h1 -> h0
    hipMemsetAsync(h0, 0, hbytes, stream);
    k_scatter<<<sgrid, 256, 0, stream>>>(h1, h0, src, dst, norm);
    // hop 3: h0 -> h1
    hipMemsetAsync(h1, 0, hbytes, stream);
    k_scatter<<<sgrid, 256, 0, stream>>>(h0, h1, src, dst, norm);
    // hop 4: h1 -> out (pre-initialized with bias)
    k_biasinit<<<(NNODES * OUTF + 255) / 256, 256, 0, stream>>>(out, b);
    k_scatter<<<sgrid, 256, 0, stream>>>(h1, out, src, dst, norm);
}

// Round 2
// 274.539 us; speedup vs baseline: 2.3031x; 2.3031x over previous
//
#include <hip/hip_runtime.h>
#include <cstdint>

#define NNODES 100000
#define NEDGES 1200000
#define INF 64
#define OUTF 32
#define SCAN_B 256
#define NBLK ((NNODES + SCAN_B - 1) / SCAN_B)   // 391

// ---- degree histogram (int) ----
__global__ __launch_bounds__(256) void k_hist(const int* __restrict__ dst,
                                              int* __restrict__ degi) {
    int i = blockIdx.x * 256 + threadIdx.x;
    if (i < NEDGES) atomicAdd(&degi[dst[i]], 1);
}

// ---- norm = rsqrt(max(deg,1)) ----
__global__ __launch_bounds__(256) void k_norm(const int* __restrict__ degi,
                                              float* __restrict__ norm) {
    int i = blockIdx.x * 256 + threadIdx.x;
    if (i < NNODES) {
        int d = degi[i];
        norm[i] = rsqrtf(d < 1 ? 1.0f : (float)d);
    }
}

// ---- scan step 1: per-block sums ----
__global__ __launch_bounds__(SCAN_B) void k_scan1(const int* __restrict__ degi,
                                                  int* __restrict__ bsum) {
    __shared__ int s[SCAN_B];
    int i = blockIdx.x * SCAN_B + threadIdx.x;
    s[threadIdx.x] = (i < NNODES) ? degi[i] : 0;
    __syncthreads();
    for (int st = SCAN_B / 2; st > 0; st >>= 1) {
        if (threadIdx.x < st) s[threadIdx.x] += s[threadIdx.x + st];
        __syncthreads();
    }
    if (threadIdx.x == 0) bsum[blockIdx.x] = s[0];
}

// ---- scan step 2: exclusive scan of block sums (single block, 512 thr) ----
__global__ __launch_bounds__(512) void k_scan2(int* __restrict__ bsum) {
    __shared__ int s[512];
    int t = threadIdx.x;
    int v = (t < NBLK) ? bsum[t] : 0;
    s[t] = v;
    __syncthreads();
    for (int st = 1; st < 512; st <<= 1) {
        int add = (t >= st) ? s[t - st] : 0;
        __syncthreads();
        s[t] += add;
        __syncthreads();
    }
    if (t < NBLK) bsum[t] = s[t] - v;  // exclusive
}

// ---- scan step 3: per-block exclusive scan + offset -> rowstart ----
__global__ __launch_bounds__(SCAN_B) void k_scan3(const int* __restrict__ degi,
                                                  const int* __restrict__ bsum,
                                                  int* __restrict__ rowstart) {
    __shared__ int s[SCAN_B];
    int i = blockIdx.x * SCAN_B + threadIdx.x;
    int t = threadIdx.x;
    int v = (i < NNODES) ? degi[i] : 0;
    s[t] = v;
    __syncthreads();
    for (int st = 1; st < SCAN_B; st <<= 1) {
        int add = (t >= st) ? s[t - st] : 0;
        __syncthreads();
        s[t] += add;
        __syncthreads();
    }
    if (i < NNODES) rowstart[i] = bsum[blockIdx.x] + s[t] - v;
    if (blockIdx.x == 0 && t == 0) rowstart[NNODES] = NEDGES;
}

// ---- fill CSR: col = src id, wv = norm[src]*norm[dst] ----
__global__ __launch_bounds__(256) void k_fill(const int* __restrict__ src,
                                              const int* __restrict__ dst,
                                              const int* __restrict__ rowstart,
                                              int* __restrict__ cursor,
                                              const float* __restrict__ norm,
                                              int* __restrict__ col,
                                              float* __restrict__ wv) {
    int i = blockIdx.x * 256 + threadIdx.x;
    if (i >= NEDGES) return;
    int d = dst[i], s = src[i];
    int p = rowstart[d] + atomicAdd(&cursor[d], 1);
    col[p] = s;
    wv[p] = norm[s] * norm[d];
}

// ---- h0 = X @ W^T (project 64->32 before propagation) ----
__global__ __launch_bounds__(256) void k_project(const float* __restrict__ feat,
                                                 const float* __restrict__ W,
                                                 float* __restrict__ h0) {
    __shared__ float Ws[OUTF][INF + 1];
    __shared__ float Fs[8][INF];
    int tid = threadIdx.x;
    for (int i = tid; i < OUTF * INF; i += 256) Ws[i / INF][i % INF] = W[i];
    int node0 = blockIdx.x * 8;
    for (int i = tid; i < 8 * INF; i += 256) {
        int n = node0 + i / INF;
        Fs[i / INF][i % INF] = (n < NNODES) ? feat[(size_t)n * INF + (i % INF)] : 0.0f;
    }
    __syncthreads();
    int ln = tid >> 5, of = tid & 31;
    int n = node0 + ln;
    if (n < NNODES) {
        float acc = 0.0f;
#pragma unroll
        for (int k = 0; k < INF; ++k) acc += Fs[ln][k] * Ws[of][k];
        h0[(size_t)n * OUTF + of] = acc;
    }
}

// ---- one hop, gather form: hout[d] = sum_e wv[e]*hin[col[e]]  (+bias) ----
// 8 lanes per node, one float4 (4 features) per lane. No atomics.
__global__ __launch_bounds__(256) void k_gather(const float4* __restrict__ hin4,
                                                float4* __restrict__ hout4,
                                                const int* __restrict__ rowstart,
                                                const int* __restrict__ col,
                                                const float* __restrict__ wv,
                                                const float4* __restrict__ bias4) {
    int t = blockIdx.x * 256 + threadIdx.x;
    int node = t >> 3;
    if (node >= NNODES) return;
    int lane = t & 7;
    int e = rowstart[node], re = rowstart[node + 1];
    float4 acc = make_float4(0.f, 0.f, 0.f, 0.f);
    // 2-edge unroll: two independent gathers in flight
    for (; e + 1 < re; e += 2) {
        int s0 = col[e], s1 = col[e + 1];
        float w0 = wv[e], w1 = wv[e + 1];
        float4 a = hin4[(size_t)s0 * 8 + lane];
        float4 b = hin4[(size_t)s1 * 8 + lane];
        acc.x += w0 * a.x + w1 * b.x;
        acc.y += w0 * a.y + w1 * b.y;
        acc.z += w0 * a.z + w1 * b.z;
        acc.w += w0 * a.w + w1 * b.w;
    }
    if (e < re) {
        int s0 = col[e];
        float w0 = wv[e];
        float4 a = hin4[(size_t)s0 * 8 + lane];
        acc.x += w0 * a.x; acc.y += w0 * a.y;
        acc.z += w0 * a.z; acc.w += w0 * a.w;
    }
    if (bias4) {
        float4 b = bias4[lane];
        acc.x += b.x; acc.y += b.y; acc.z += b.z; acc.w += b.w;
    }
    hout4[(size_t)node * 8 + lane] = acc;
}

extern "C" void kernel_launch(void* const* d_in, const int* in_sizes, int n_in,
                              void* d_out, int out_size, void* d_ws, size_t ws_size,
                              hipStream_t stream) {
    const float* feat = (const float*)d_in[0];
    const int*   src  = (const int*)d_in[1];
    const int*   dst  = (const int*)d_in[2];
    const float* W    = (const float*)d_in[3];
    const float* b    = (const float*)d_in[4];
    float* out = (float*)d_out;

    char* ws = (char*)d_ws;
    size_t off = 0;
    auto alloc = [&](size_t bytes) {
        void* p = ws + off;
        off = (off + bytes + 255) & ~(size_t)255;
        return p;
    };
    int*   degi     = (int*)alloc((size_t)NNODES * 4);
    float* norm     = (float*)alloc((size_t)NNODES * 4);
    int*   rowstart = (int*)alloc(((size_t)NNODES + 1) * 4);
    int*   cursor   = (int*)alloc((size_t)NNODES * 4);
    int*   bsum     = (int*)alloc((size_t)NBLK * 4);
    int*   col      = (int*)alloc((size_t)NEDGES * 4);
    float* wv       = (float*)alloc((size_t)NEDGES * 4);
    float* h0       = (float*)alloc((size_t)NNODES * OUTF * 4);
    float* h1       = (float*)alloc((size_t)NNODES * OUTF * 4);

    // ---- build CSR ----
    hipMemsetAsync(degi, 0, (size_t)NNODES * 4, stream);
    hipMemsetAsync(cursor, 0, (size_t)NNODES * 4, stream);
    k_hist<<<(NEDGES + 255) / 256, 256, 0, stream>>>(dst, degi);
    k_norm<<<(NNODES + 255) / 256, 256, 0, stream>>>(degi, norm);
    k_scan1<<<NBLK, SCAN_B, 0, stream>>>(degi, bsum);
    k_scan2<<<1, 512, 0, stream>>>(bsum);
    k_scan3<<<NBLK, SCAN_B, 0, stream>>>(degi, bsum, rowstart);
    k_fill<<<(NEDGES + 255) / 256, 256, 0, stream>>>(src, dst, rowstart, cursor,
                                                     norm, col, wv);

    // ---- project 64 -> 32 ----
    k_project<<<(NNODES + 7) / 8, 256, 0, stream>>>(feat, W, h0);

    // ---- 4 hops, no atomics ----
    const int ggrid = (NNODES * 8 + 255) / 256;
    k_gather<<<ggrid, 256, 0, stream>>>((const float4*)h0, (float4*)h1,
                                        rowstart, col, wv, nullptr);
    k_gather<<<ggrid, 256, 0, stream>>>((const float4*)h1, (float4*)h0,
                                        rowstart, col, wv, nullptr);
    k_gather<<<ggrid, 256, 0, stream>>>((const float4*)h0, (float4*)h1,
                                        rowstart, col, wv, nullptr);
    k_gather<<<ggrid, 256, 0, stream>>>((const float4*)h1, (float4*)out,
                                        rowstart, col, wv, (const float4*)b);
}